// Round 4
// baseline (1651.486 us; speedup 1.0000x reference)
//
#include <hip/hip_runtime.h>
#include <stdint.h>

#define B_ 32
#define C_ 512
#define HW_ 4096
#define N_ 131072
#define K_ 512
#define QELEMS 67108864   /* B*C*H*W = 2^26 */
#define MARGIN 4e-4f
#define RFCAP 65536

// ---------------------------------------------------------------------------
// numpy float32 pairwise sum of 512 contiguous floats, replicating:
//   recursion 512 -> 256+256 -> 128-blocks (SIMD base case, AVX512 16-lane,
//   8 vector accumulators, GCC _mm512_reduce_add_ps horizontal tree).
// Input: pre-squared (or raw) elements; pure f32 adds, no contraction.
// ---------------------------------------------------------------------------
__device__ __forceinline__ float np_pw512(const float* a) {
  float P[4];
#pragma unroll
  for (int m = 0; m < 4; ++m) {
    const float* q = a + m * 128;
    float rv[16];
#pragma unroll
    for (int l = 0; l < 16; ++l) {
      float v0 = q[l],      v1 = q[16 + l],  v2 = q[32 + l],  v3 = q[48 + l];
      float v4 = q[64 + l], v5 = q[80 + l],  v6 = q[96 + l],  v7 = q[112 + l];
      rv[l] = ((v0 + v1) + (v2 + v3)) + ((v4 + v5) + (v6 + v7));
    }
    float u[8], w[4];
#pragma unroll
    for (int l = 0; l < 8; ++l) u[l] = rv[8 + l] + rv[l];
#pragma unroll
    for (int l = 0; l < 4; ++l) w[l] = u[4 + l] + u[l];
    P[m] = (w[0] + w[2]) + (w[1] + w[3]);
  }
  return (P[0] + P[1]) + (P[2] + P[3]);
}

// ---------------------------------------------------------------------------
// K0: transpose embed -> eT[c][k]; se_np[k] = np-f32 pairwise sum of e^2.
// ---------------------------------------------------------------------------
__global__ __launch_bounds__(256) void k_prep(const float* __restrict__ embed,
    float* __restrict__ eT, float* __restrict__ senp, int* __restrict__ rcnt)
{
  __shared__ float erow[C_];
  __shared__ float sqa[C_];
  int k = blockIdx.x;
  for (int c = threadIdx.x; c < C_; c += 256) {
    float e = embed[k * C_ + c];
    erow[c] = e;
    eT[c * K_ + k] = e;
  }
  __syncthreads();
  for (int c = threadIdx.x; c < C_; c += 256)
    sqa[c] = __fmul_rn(erow[c], erow[c]);
  __syncthreads();
  if (threadIdx.x == 0) {
    senp[k] = np_pw512(sqa);
    if (blockIdx.x == 0) *rcnt = 0;
  }
}

// ---------------------------------------------------------------------------
// K1: main fp32 pass. Block = 64 rows x 256 codes (chunked 2x), 8x8/thread.
//     Per-thread top-2, padded-LDS serial per-row merge.
//     Rows with top-2 gap < MARGIN flagged for np-f32-replica refine.
//     c_k = ||e_k||^2 - 2 x.e_k   (row-constant ||x||^2 dropped: argmin-safe
//     vs exact order; near-ties are all flagged and re-decided by refine)
// ---------------------------------------------------------------------------
__global__ __launch_bounds__(256) void k_argmin(const float* __restrict__ x,
    const float* __restrict__ eT, const float* __restrict__ senp,
    int* __restrict__ idx_out, int* __restrict__ rcnt, int* __restrict__ rrows)
{
  __shared__ float xs[32][64];    // [c][row]
  __shared__ float es[32][256];   // [c][code]
  __shared__ float ses[K_];
  __shared__ float mb[64][33];    // per-row merge: best   (+1 pad)
  __shared__ float ms[64][33];    //                second
  __shared__ int   mi[64][33];    //                index
  const int t = threadIdx.x;
  const int b = blockIdx.x >> 6;
  const int row0 = (blockIdx.x & 63) << 6;
  for (int i = t; i < K_; i += 256) ses[i] = senp[i];
  const int rt = t >> 5, ct = t & 31;   // 8 row-tiles x 32 code-tiles

  float best[8], second[8]; int bidx[8];
#pragma unroll
  for (int i = 0; i < 8; ++i) { best[i] = 1e30f; second[i] = 1e30f; bidx[i] = 0; }

  for (int kk = 0; kk < 2; ++kk) {
    const int k0 = kk << 8;
    float acc[8][8];
#pragma unroll
    for (int i = 0; i < 8; ++i)
#pragma unroll
      for (int j = 0; j < 8; ++j) acc[i][j] = 0.f;

    for (int c0 = 0; c0 < C_; c0 += 32) {
      __syncthreads();
#pragma unroll
      for (int i = 0; i < 2; ++i) {
        int l = t + (i << 8);                 // 0..511 float4s
        int cc = l >> 4, r4 = (l & 15) << 2;
        *(float4*)&xs[cc][r4] =
            *(const float4*)(x + (((size_t)(b * C_ + c0 + cc)) << 12) + row0 + r4);
      }
#pragma unroll
      for (int i = 0; i < 8; ++i) {
        int l = t + (i << 8);                 // 0..2047 float4s
        int cc = l >> 6, k4 = (l & 63) << 2;
        *(float4*)&es[cc][k4] =
            *(const float4*)(eT + ((c0 + cc) << 9) + k0 + k4);
      }
      __syncthreads();
#pragma unroll 4
      for (int cc = 0; cc < 32; ++cc) {
        float xr[8], er[8];
        *(float4*)&xr[0] = *(const float4*)&xs[cc][rt * 8];
        *(float4*)&xr[4] = *(const float4*)&xs[cc][rt * 8 + 4];
        *(float4*)&er[0] = *(const float4*)&es[cc][ct * 8];
        *(float4*)&er[4] = *(const float4*)&es[cc][ct * 8 + 4];
#pragma unroll
        for (int i = 0; i < 8; ++i)
#pragma unroll
          for (int j = 0; j < 8; ++j)
            acc[i][j] += xr[i] * er[j];
      }
    }
#pragma unroll
    for (int j = 0; j < 8; ++j) {
      int k = k0 + ct * 8 + j;
      float se = ses[k];
#pragma unroll
      for (int i = 0; i < 8; ++i) {
        float v = se - 2.0f * acc[i][j];
        if (v < best[i]) { second[i] = best[i]; best[i] = v; bidx[i] = k; }
        else if (v < second[i]) second[i] = v;
      }
    }
  }
#pragma unroll
  for (int i = 0; i < 8; ++i) {
    mb[rt * 8 + i][ct] = best[i];
    ms[rt * 8 + i][ct] = second[i];
    mi[rt * 8 + i][ct] = bidx[i];
  }
  __syncthreads();
  if (t < 64) {
    float Bv = 1e30f, Sv = 1e30f; int Iv = 0;
    for (int c = 0; c < 32; ++c) {
      float b1 = mb[t][c], s1 = ms[t][c]; int i1 = mi[t][c];
      if (b1 < Bv) { Sv = fminf(Bv, s1); Bv = b1; Iv = i1; }
      else         { Sv = fminf(Sv, b1); }
    }
    int n = b * HW_ + row0 + t;
    idx_out[n] = Iv;
    if (Sv - Bv < MARGIN) {
      int p = atomicAdd(rcnt, 1);
      if (p < RFCAP) rrows[p] = n;
    }
  }
}

// ---------------------------------------------------------------------------
// K2: np-f32-replica re-rank of flagged rows over all 512 codes.
//     d_k = fl32( fl32(Sx_np + Se_np[k]) - 2*M_k ),
//     M_k = fl32( seqFMA(c=0..383) + seqFMA(c=384..511) )   (OpenBLAS KC=384)
//     argmin with first-index tie-break (np.argmin semantics).
// ---------------------------------------------------------------------------
__global__ __launch_bounds__(512) void k_refine(const float* __restrict__ x,
    const float* __restrict__ embed, const float* __restrict__ senp,
    const int* __restrict__ rcnt, const int* __restrict__ rrows,
    int* __restrict__ idx_out)
{
  __shared__ float xrow[C_];
  __shared__ float sqa[C_];
  __shared__ float vals[512];
  __shared__ int   vidx[512];
  __shared__ float SxSh;
  const int t = threadIdx.x;
  int cnt = *rcnt; if (cnt > RFCAP) cnt = RFCAP;
  for (int r = blockIdx.x; r < cnt; r += gridDim.x) {
    int n = rrows[r];
    int b = n >> 12, hw = n & 4095;
    __syncthreads();
    xrow[t] = x[(((size_t)(b * C_ + t)) << 12) + hw];
    __syncthreads();
    sqa[t] = __fmul_rn(xrow[t], xrow[t]);
    __syncthreads();
    if (t == 0) SxSh = np_pw512(sqa);
    __syncthreads();
    // one code per thread: sequential-FMA dot split at 384
    const float* e = embed + (size_t)t * C_;
    float a1 = 0.f, a2 = 0.f;
    for (int c = 0; c < 384; ++c)  a1 = fmaf(xrow[c], e[c], a1);
    for (int c = 384; c < 512; ++c) a2 = fmaf(xrow[c], e[c], a2);
    float M  = a1 + a2;
    float tt = SxSh + senp[t];
    float d  = tt - 2.0f * M;
    vals[t] = d; vidx[t] = t;
    for (int st = 256; st > 0; st >>= 1) {
      __syncthreads();
      if (t < st) {
        float ov = vals[t + st]; int oi = vidx[t + st];
        if (ov < vals[t] || (ov == vals[t] && oi < vidx[t])) {
          vals[t] = ov; vidx[t] = oi;
        }
      }
    }
    __syncthreads();
    if (t == 0) idx_out[n] = vidx[0];
  }
}

// ---------------------------------------------------------------------------
// K3: gather quantized -> out (BCHW layout == linear m), f64 loss partials.
// ---------------------------------------------------------------------------
__global__ __launch_bounds__(256) void k_gather(const float* __restrict__ x,
    const float* __restrict__ embed, const int* __restrict__ idx,
    float* __restrict__ out_q, double* __restrict__ loss_part)
{
  double s = 0.0;
  int tid = blockIdx.x * 256 + threadIdx.x;
  for (int m = tid; m < QELEMS; m += 524288) {
    int bc = m >> 12;            // b*C + c
    int c  = bc & (C_ - 1);
    int b  = bc >> 9;
    int hw = m & 4095;
    int k  = idx[(b << 12) + hw];
    float q  = embed[((size_t)k << 9) + c];
    float xv = x[m];
    out_q[m] = q;
    double d = (double)q - (double)xv;
    s += d * d;
  }
  for (int off = 32; off > 0; off >>= 1) s += __shfl_down(s, off, 64);
  __shared__ double wsum[4];
  if ((threadIdx.x & 63) == 0) wsum[threadIdx.x >> 6] = s;
  __syncthreads();
  if (threadIdx.x == 0)
    loss_part[blockIdx.x] = (wsum[0] + wsum[1]) + (wsum[2] + wsum[3]);
}

// ---------------------------------------------------------------------------
// K4: per-batch unique-code count + write idx_b as float.
// ---------------------------------------------------------------------------
__global__ __launch_bounds__(256) void k_pplx(const int* __restrict__ idx,
    float* __restrict__ out_idxf, int* __restrict__ counts)
{
  __shared__ int flags[K_];
  __shared__ int red[256];
  int b = blockIdx.x;
  for (int i = threadIdx.x; i < K_; i += 256) flags[i] = 0;
  __syncthreads();
  for (int hw = threadIdx.x; hw < HW_; hw += 256) {
    int k = idx[(b << 12) + hw];
    flags[k] = 1;
    out_idxf[(b << 12) + hw] = (float)k;
  }
  __syncthreads();
  int c = 0;
  for (int i = threadIdx.x; i < K_; i += 256) c += flags[i];
  red[threadIdx.x] = c;
  __syncthreads();
  for (int st = 128; st > 0; st >>= 1) {
    if (threadIdx.x < st) red[threadIdx.x] += red[threadIdx.x + st];
    __syncthreads();
  }
  if (threadIdx.x == 0) counts[b] = red[0];
}

// ---------------------------------------------------------------------------
// K5: finalize scalars.
// ---------------------------------------------------------------------------
__global__ __launch_bounds__(256) void k_final(const double* __restrict__ loss_part,
    const int* __restrict__ counts, float* __restrict__ out_loss,
    float* __restrict__ out_pplx)
{
  __shared__ double sred[256];
  double s = 0.0;
  for (int i = threadIdx.x; i < 2048; i += 256) s += loss_part[i];
  sred[threadIdx.x] = s;
  __syncthreads();
  for (int st = 128; st > 0; st >>= 1) {
    if (threadIdx.x < st) sred[threadIdx.x] += sred[threadIdx.x + st];
    __syncthreads();
  }
  if (threadIdx.x == 0) {
    *out_loss = (float)(1.25 * sred[0] / (double)QELEMS);
    int c = 0;
    for (int i = 0; i < B_; ++i) c += counts[i];
    *out_pplx = (float)c / (float)B_;
  }
}

// ---------------------------------------------------------------------------
extern "C" void kernel_launch(void* const* d_in, const int* in_sizes, int n_in,
                              void* d_out, int out_size, void* d_ws, size_t ws_size,
                              hipStream_t stream)
{
  const float* x     = (const float*)d_in[0];
  const float* embed = (const float*)d_in[1];
  float* out      = (float*)d_out;
  float* out_loss = out;                  // [0]
  float* out_q    = out + 1;              // [1 .. 1+QELEMS)
  float* out_pplx = out + 1 + QELEMS;     // [1+QELEMS]
  float* out_idxf = out + 2 + QELEMS;     // [2+QELEMS .. 2+QELEMS+N_)

  char* ws = (char*)d_ws;
  // persistent across the whole call
  int*    w_idx = (int*)ws;                             // 512 KB
  double* w_lp  = (double*)(ws + 524288);               // 16 KB (2048 partials)
  int*    w_cnt = (int*)(ws + 524288 + 16384);          // 128 B
  size_t pers = 524288 + 16384 + 128;

  // volatile (dead after K2): eT 1MB, senp 2KB, rcnt, rrows 256KB
  size_t VOLB = (size_t)1048576 + 2048 + 256 + (size_t)RFCAP * 4;
  char* vbase;
  if (ws_size >= pers + VOLB + 4096) {
    vbase = ws + ((pers + 255) & ~(size_t)255);
  } else {
    // fall back: stash in the tail of the quant output region (overwritten by K3)
    uintptr_t a = ((uintptr_t)(out_q + QELEMS) - VOLB) & ~(uintptr_t)255;
    vbase = (char*)a;
  }
  float*  w_eT    = (float*)vbase;
  float*  w_senp  = (float*)(vbase + 1048576);
  int*    w_rcnt  = (int*)(vbase + 1048576 + 2048);
  int*    w_rrows = (int*)(vbase + 1048576 + 2048 + 256);

  k_prep  <<<dim3(512),  dim3(256), 0, stream>>>(embed, w_eT, w_senp, w_rcnt);
  k_argmin<<<dim3(2048), dim3(256), 0, stream>>>(x, w_eT, w_senp, w_idx, w_rcnt, w_rrows);
  k_refine<<<dim3(256),  dim3(512), 0, stream>>>(x, embed, w_senp, w_rcnt, w_rrows, w_idx);
  k_gather<<<dim3(2048), dim3(256), 0, stream>>>(x, embed, w_idx, out_q, w_lp);
  k_pplx  <<<dim3(32),   dim3(256), 0, stream>>>(w_idx, out_idxf, w_cnt);
  k_final <<<dim3(1),    dim3(256), 0, stream>>>(w_lp, w_cnt, out_loss, out_pplx);
}

// Round 5
// 1623.747 us; speedup vs baseline: 1.0171x; 1.0171x over previous
//
#include <hip/hip_runtime.h>
#include <stdint.h>

#define B_ 32
#define C_ 512
#define HW_ 4096
#define N_ 131072
#define K_ 512
#define QELEMS 67108864   /* B*C*H*W = 2^26 */
#define MARGIN 4e-4f
#define RFCAP 65536

// ---------------------------------------------------------------------------
// numpy float32 pairwise sum of 512 contiguous floats (AVX512 base case,
// 8 vector accumulators, GCC _mm512_reduce_add_ps horizontal tree).
// ---------------------------------------------------------------------------
__device__ __forceinline__ float np_pw512(const float* a) {
  float P[4];
#pragma unroll
  for (int m = 0; m < 4; ++m) {
    const float* q = a + m * 128;
    float rv[16];
#pragma unroll
    for (int l = 0; l < 16; ++l) {
      float v0 = q[l],      v1 = q[16 + l],  v2 = q[32 + l],  v3 = q[48 + l];
      float v4 = q[64 + l], v5 = q[80 + l],  v6 = q[96 + l],  v7 = q[112 + l];
      rv[l] = ((v0 + v1) + (v2 + v3)) + ((v4 + v5) + (v6 + v7));
    }
    float u[8], w[4];
#pragma unroll
    for (int l = 0; l < 8; ++l) u[l] = rv[8 + l] + rv[l];
#pragma unroll
    for (int l = 0; l < 4; ++l) w[l] = u[4 + l] + u[l];
    P[m] = (w[0] + w[2]) + (w[1] + w[3]);
  }
  return (P[0] + P[1]) + (P[2] + P[3]);
}

// ---------------------------------------------------------------------------
// K0: transpose embed -> eT[c][k]; se_np[k] = np-f32 pairwise sum of e^2.
// ---------------------------------------------------------------------------
__global__ __launch_bounds__(256) void k_prep(const float* __restrict__ embed,
    float* __restrict__ eT, float* __restrict__ senp, int* __restrict__ rcnt)
{
  __shared__ float erow[C_];
  __shared__ float sqa[C_];
  int k = blockIdx.x;
  for (int c = threadIdx.x; c < C_; c += 256) {
    float e = embed[k * C_ + c];
    erow[c] = e;
    eT[c * K_ + k] = e;
  }
  __syncthreads();
  for (int c = threadIdx.x; c < C_; c += 256)
    sqa[c] = __fmul_rn(erow[c], erow[c]);
  __syncthreads();
  if (threadIdx.x == 0) {
    senp[k] = np_pw512(sqa);
    if (blockIdx.x == 0) *rcnt = 0;
  }
}

// ---------------------------------------------------------------------------
// K1: main fp32 pass, conflict-free mapping.
//     Block = 64 rows x 256 codes (x2 kk). Thread: rg=t>>6 (16 rows),
//     cg=t&63 (4 codes). er = one lane-contiguous b128 (conflict-free);
//     xr = wave-uniform b128 broadcasts (free). In-register top-2 with
//     64-lane shfl_xor butterfly merge (lowest-index tie-break).
//     Rows with top-2 gap < MARGIN flagged for np-f32-replica refine.
// ---------------------------------------------------------------------------
__global__ __launch_bounds__(256, 3) void k_argmin(const float* __restrict__ x,
    const float* __restrict__ eT, const float* __restrict__ senp,
    int* __restrict__ idx_out, int* __restrict__ rcnt, int* __restrict__ rrows)
{
  __shared__ float xs[32][64];    // [c][row]    8 KB
  __shared__ float es[32][256];   // [c][code]  32 KB
  __shared__ float ses[K_];       //             2 KB
  const int t = threadIdx.x;
  const int b = blockIdx.x >> 6;
  const int row0 = (blockIdx.x & 63) << 6;
  const int rg = t >> 6;          // wave id: rows rg*16 .. rg*16+15
  const int cg = t & 63;          // codes cg*4 .. cg*4+3 (+ kk*256)
  for (int i = t; i < K_; i += 256) ses[i] = senp[i];

  float best[16], second[16]; int bidx[16];
#pragma unroll
  for (int i = 0; i < 16; ++i) { best[i] = 1e30f; second[i] = 1e30f; bidx[i] = 0; }

  for (int kk = 0; kk < 2; ++kk) {
    const int k0 = kk << 8;
    float acc[16][4];
#pragma unroll
    for (int i = 0; i < 16; ++i)
#pragma unroll
      for (int j = 0; j < 4; ++j) acc[i][j] = 0.f;

    for (int c0 = 0; c0 < C_; c0 += 32) {
      __syncthreads();
      // stage x tile: 32 c x 64 rows (hw contiguous -> coalesced)
#pragma unroll
      for (int i = 0; i < 2; ++i) {
        int l = t + (i << 8);                 // 0..511 float4s
        int cc = l >> 4, r4 = (l & 15) << 2;
        *(float4*)&xs[cc][r4] =
            *(const float4*)(x + (((size_t)(b * C_ + c0 + cc)) << 12) + row0 + r4);
      }
      // stage e tile from eT: 32 c x 256 codes (k contiguous -> coalesced)
#pragma unroll
      for (int i = 0; i < 8; ++i) {
        int l = t + (i << 8);                 // 0..2047 float4s
        int cc = l >> 6, k4 = (l & 63) << 2;
        *(float4*)&es[cc][k4] =
            *(const float4*)(eT + ((c0 + cc) << 9) + k0 + k4);
      }
      __syncthreads();
#pragma unroll 4
      for (int cc = 0; cc < 32; ++cc) {
        float4 er4 = *((const float4*)&es[cc][0] + cg);        // conflict-free
        float er[4] = {er4.x, er4.y, er4.z, er4.w};
        float xr[16];
        *(float4*)&xr[0]  = *((const float4*)&xs[cc][0] + (rg << 2) + 0);  // bcast
        *(float4*)&xr[4]  = *((const float4*)&xs[cc][0] + (rg << 2) + 1);
        *(float4*)&xr[8]  = *((const float4*)&xs[cc][0] + (rg << 2) + 2);
        *(float4*)&xr[12] = *((const float4*)&xs[cc][0] + (rg << 2) + 3);
#pragma unroll
        for (int i = 0; i < 16; ++i)
#pragma unroll
          for (int j = 0; j < 4; ++j)
            acc[i][j] += xr[i] * er[j];
      }
    }
    // fold ||e||^2, update per-row top-2 over this thread's 4 codes
    float4 sev = *((const float4*)ses + (kk << 6) + cg);       // conflict-free
    float se[4] = {sev.x, sev.y, sev.z, sev.w};
#pragma unroll
    for (int j = 0; j < 4; ++j) {
      int k = k0 + (cg << 2) + j;
#pragma unroll
      for (int i = 0; i < 16; ++i) {
        float v = se[j] - 2.0f * acc[i][j];
        if (v < best[i]) { second[i] = best[i]; best[i] = v; bidx[i] = k; }
        else if (v < second[i]) second[i] = v;
      }
    }
  }
  // 64-lane butterfly top-2 merge, lowest-index tie-break
#pragma unroll
  for (int off = 1; off < 64; off <<= 1) {
#pragma unroll
    for (int i = 0; i < 16; ++i) {
      float ob = __shfl_xor(best[i], off, 64);
      float os = __shfl_xor(second[i], off, 64);
      int   oi = __shfl_xor(bidx[i], off, 64);
      float ns = fminf(fmaxf(best[i], ob), fminf(second[i], os));
      if (ob < best[i] || (ob == best[i] && oi < bidx[i])) { best[i] = ob; bidx[i] = oi; }
      second[i] = ns;
    }
  }
  if ((t & 63) == 0) {
#pragma unroll
    for (int i = 0; i < 16; ++i) {
      int n = b * HW_ + row0 + (rg << 4) + i;
      idx_out[n] = bidx[i];
      if (second[i] - best[i] < MARGIN) {
        int p = atomicAdd(rcnt, 1);
        if (p < RFCAP) rrows[p] = n;
      }
    }
  }
}

// ---------------------------------------------------------------------------
// K2: np-f32-replica re-rank of flagged rows over all 512 codes.
//     d_k = fl32( fl32(Sx_np + Se_np[k]) - 2*M_k ),
//     M_k = fl32( seqFMA(c=0..383) + seqFMA(c=384..511) )   (OpenBLAS KC=384)
//     argmin with first-index tie-break (np.argmin semantics).
// ---------------------------------------------------------------------------
__global__ __launch_bounds__(512) void k_refine(const float* __restrict__ x,
    const float* __restrict__ embed, const float* __restrict__ senp,
    const int* __restrict__ rcnt, const int* __restrict__ rrows,
    int* __restrict__ idx_out)
{
  __shared__ float xrow[C_];
  __shared__ float sqa[C_];
  __shared__ float vals[512];
  __shared__ int   vidx[512];
  __shared__ float SxSh;
  const int t = threadIdx.x;
  int cnt = *rcnt; if (cnt > RFCAP) cnt = RFCAP;
  for (int r = blockIdx.x; r < cnt; r += gridDim.x) {
    int n = rrows[r];
    int b = n >> 12, hw = n & 4095;
    __syncthreads();
    xrow[t] = x[(((size_t)(b * C_ + t)) << 12) + hw];
    __syncthreads();
    sqa[t] = __fmul_rn(xrow[t], xrow[t]);
    __syncthreads();
    if (t == 0) SxSh = np_pw512(sqa);
    __syncthreads();
    // one code per thread: sequential-FMA dot split at 384
    const float* e = embed + (size_t)t * C_;
    float a1 = 0.f, a2 = 0.f;
    for (int c = 0; c < 384; ++c)  a1 = fmaf(xrow[c], e[c], a1);
    for (int c = 384; c < 512; ++c) a2 = fmaf(xrow[c], e[c], a2);
    float M  = a1 + a2;
    float tt = SxSh + senp[t];
    float d  = tt - 2.0f * M;
    vals[t] = d; vidx[t] = t;
    for (int st = 256; st > 0; st >>= 1) {
      __syncthreads();
      if (t < st) {
        float ov = vals[t + st]; int oi = vidx[t + st];
        if (ov < vals[t] || (ov == vals[t] && oi < vidx[t])) {
          vals[t] = ov; vidx[t] = oi;
        }
      }
    }
    __syncthreads();
    if (t == 0) idx_out[n] = vidx[0];
  }
}

// ---------------------------------------------------------------------------
// K3: gather quantized -> out (BCHW layout == linear m), f64 loss partials.
//     Vectorized loads (float4 x, int4 idx); scalar stores (out+1 misaligned).
// ---------------------------------------------------------------------------
__global__ __launch_bounds__(256) void k_gather(const float* __restrict__ x,
    const float* __restrict__ embed, const int* __restrict__ idx,
    float* __restrict__ out_q, double* __restrict__ loss_part)
{
  double s = 0.0;
  int tid = blockIdx.x * 256 + threadIdx.x;
  for (int m4 = tid; m4 < (QELEMS >> 2); m4 += 524288) {
    int m  = m4 << 2;
    int bc = m >> 12;            // b*C + c
    int c  = bc & (C_ - 1);
    int bbase = (bc >> 9) << 12; // b*HW
    int hw = m & 4095;
    int4  kv = *(const int4*)&idx[bbase + hw];
    float4 xv = ((const float4*)x)[m4];
    float q0 = embed[((size_t)kv.x << 9) + c];
    float q1 = embed[((size_t)kv.y << 9) + c];
    float q2 = embed[((size_t)kv.z << 9) + c];
    float q3 = embed[((size_t)kv.w << 9) + c];
    out_q[m + 0] = q0; out_q[m + 1] = q1;
    out_q[m + 2] = q2; out_q[m + 3] = q3;
    double d0 = (double)q0 - (double)xv.x;
    double d1 = (double)q1 - (double)xv.y;
    double d2 = (double)q2 - (double)xv.z;
    double d3 = (double)q3 - (double)xv.w;
    s += d0 * d0 + d1 * d1 + d2 * d2 + d3 * d3;
  }
  for (int off = 32; off > 0; off >>= 1) s += __shfl_down(s, off, 64);
  __shared__ double wsum[4];
  if ((threadIdx.x & 63) == 0) wsum[threadIdx.x >> 6] = s;
  __syncthreads();
  if (threadIdx.x == 0)
    loss_part[blockIdx.x] = (wsum[0] + wsum[1]) + (wsum[2] + wsum[3]);
}

// ---------------------------------------------------------------------------
// K4: per-batch unique-code count + write idx_b as float.
// ---------------------------------------------------------------------------
__global__ __launch_bounds__(256) void k_pplx(const int* __restrict__ idx,
    float* __restrict__ out_idxf, int* __restrict__ counts)
{
  __shared__ int flags[K_];
  __shared__ int red[256];
  int b = blockIdx.x;
  for (int i = threadIdx.x; i < K_; i += 256) flags[i] = 0;
  __syncthreads();
  for (int hw = threadIdx.x; hw < HW_; hw += 256) {
    int k = idx[(b << 12) + hw];
    flags[k] = 1;
    out_idxf[(b << 12) + hw] = (float)k;
  }
  __syncthreads();
  int c = 0;
  for (int i = threadIdx.x; i < K_; i += 256) c += flags[i];
  red[threadIdx.x] = c;
  __syncthreads();
  for (int st = 128; st > 0; st >>= 1) {
    if (threadIdx.x < st) red[threadIdx.x] += red[threadIdx.x + st];
    __syncthreads();
  }
  if (threadIdx.x == 0) counts[b] = red[0];
}

// ---------------------------------------------------------------------------
// K5: finalize scalars.
// ---------------------------------------------------------------------------
__global__ __launch_bounds__(256) void k_final(const double* __restrict__ loss_part,
    const int* __restrict__ counts, float* __restrict__ out_loss,
    float* __restrict__ out_pplx)
{
  __shared__ double sred[256];
  double s = 0.0;
  for (int i = threadIdx.x; i < 2048; i += 256) s += loss_part[i];
  sred[threadIdx.x] = s;
  __syncthreads();
  for (int st = 128; st > 0; st >>= 1) {
    if (threadIdx.x < st) sred[threadIdx.x] += sred[threadIdx.x + st];
    __syncthreads();
  }
  if (threadIdx.x == 0) {
    *out_loss = (float)(1.25 * sred[0] / (double)QELEMS);
    int c = 0;
    for (int i = 0; i < B_; ++i) c += counts[i];
    *out_pplx = (float)c / (float)B_;
  }
}

// ---------------------------------------------------------------------------
extern "C" void kernel_launch(void* const* d_in, const int* in_sizes, int n_in,
                              void* d_out, int out_size, void* d_ws, size_t ws_size,
                              hipStream_t stream)
{
  const float* x     = (const float*)d_in[0];
  const float* embed = (const float*)d_in[1];
  float* out      = (float*)d_out;
  float* out_loss = out;                  // [0]
  float* out_q    = out + 1;              // [1 .. 1+QELEMS)
  float* out_pplx = out + 1 + QELEMS;     // [1+QELEMS]
  float* out_idxf = out + 2 + QELEMS;     // [2+QELEMS .. 2+QELEMS+N_)

  char* ws = (char*)d_ws;
  // persistent across the whole call
  int*    w_idx = (int*)ws;                             // 512 KB
  double* w_lp  = (double*)(ws + 524288);               // 16 KB (2048 partials)
  int*    w_cnt = (int*)(ws + 524288 + 16384);          // 128 B
  size_t pers = 524288 + 16384 + 128;

  // volatile (dead after K2): eT 1MB, senp 2KB, rcnt, rrows 256KB
  size_t VOLB = (size_t)1048576 + 2048 + 256 + (size_t)RFCAP * 4;
  char* vbase;
  if (ws_size >= pers + VOLB + 4096) {
    vbase = ws + ((pers + 255) & ~(size_t)255);
  } else {
    // fall back: stash in the tail of the quant output region (overwritten by K3)
    uintptr_t a = ((uintptr_t)(out_q + QELEMS) - VOLB) & ~(uintptr_t)255;
    vbase = (char*)a;
  }
  float*  w_eT    = (float*)vbase;
  float*  w_senp  = (float*)(vbase + 1048576);
  int*    w_rcnt  = (int*)(vbase + 1048576 + 2048);
  int*    w_rrows = (int*)(vbase + 1048576 + 2048 + 256);

  k_prep  <<<dim3(512),  dim3(256), 0, stream>>>(embed, w_eT, w_senp, w_rcnt);
  k_argmin<<<dim3(2048), dim3(256), 0, stream>>>(x, w_eT, w_senp, w_idx, w_rcnt, w_rrows);
  k_refine<<<dim3(2048), dim3(512), 0, stream>>>(x, embed, w_senp, w_rcnt, w_rrows, w_idx);
  k_gather<<<dim3(2048), dim3(256), 0, stream>>>(x, embed, w_idx, out_q, w_lp);
  k_pplx  <<<dim3(32),   dim3(256), 0, stream>>>(w_idx, out_idxf, w_cnt);
  k_final <<<dim3(1),    dim3(256), 0, stream>>>(w_lp, w_cnt, out_loss, out_pplx);
}